// Round 3
// baseline (1845.694 us; speedup 1.0000x reference)
//
#include <hip/hip_runtime.h>
#include <hip/hip_bf16.h>

#define T_TOK 8192
#define H_DIM 1024
#define I_DIM 2816
#define E_NUM 8
#define R_TOT (2 * T_TOK)

typedef __hip_bfloat16 bf16;
typedef __attribute__((ext_vector_type(8))) short short8;
typedef __attribute__((ext_vector_type(4))) float floatx4;

__device__ inline unsigned short f2b(float f) {
    bf16 b = __float2bfloat16(f);
    unsigned short u;
    __builtin_memcpy(&u, &b, 2);
    return u;
}

// load 8 consecutive fp32, round to bf16, pack as short8 (4 VGPRs)
__device__ inline short8 ld_cvt8(const float* p) {
    float4 f0 = *(const float4*)p;
    float4 f1 = *(const float4*)(p + 4);
    short8 r;
    r[0] = (short)f2b(f0.x); r[1] = (short)f2b(f0.y);
    r[2] = (short)f2b(f0.z); r[3] = (short)f2b(f0.w);
    r[4] = (short)f2b(f1.x); r[5] = (short)f2b(f1.y);
    r[6] = (short)f2b(f1.z); r[7] = (short)f2b(f1.w);
    return r;
}

// async global(bf16, 16B-aligned) -> LDS, 16 bytes per lane.
// LDS dest is wave-uniform base + lane*16 (pass the wave's chunk base).
__device__ inline void gl_lds16(const void* g, void* l) {
    __builtin_amdgcn_global_load_lds(
        (const __attribute__((address_space(1))) void*)g,
        (__attribute__((address_space(3))) void*)l, 16, 0, 0);
}

// ---------------- fp32 -> bf16 pre-conversion (memory-bound) ----------------

__global__ __launch_bounds__(256) void cvt_bf16_kernel(const float* __restrict__ in,
                                                       bf16* __restrict__ out, int n8) {
    int stride = gridDim.x * blockDim.x;
    for (int i = blockIdx.x * blockDim.x + threadIdx.x; i < n8; i += stride) {
        short8 v = ld_cvt8(in + (size_t)i * 8);
        *(short8*)(out + (size_t)i * 8) = v;
    }
}

// ---------------- routing ----------------

__global__ void zero_counts_kernel(int* counts) {
    if (threadIdx.x < E_NUM) counts[threadIdx.x] = 0;
}

__global__ void zero_out_kernel(float* __restrict__ out) {
    size_t i = ((size_t)blockIdx.x * 256 + threadIdx.x) * 4;
    float4 z = {0.0f, 0.0f, 0.0f, 0.0f};
    *(float4*)(out + i) = z;
}

__global__ void router_kernel(const float* __restrict__ logits,
                              int* __restrict__ topk_id,
                              float* __restrict__ topk_w,
                              int* __restrict__ counts) {
    int t = blockIdx.x * blockDim.x + threadIdx.x;
    if (t >= T_TOK) return;
    float l[E_NUM];
#pragma unroll
    for (int e = 0; e < E_NUM; e++) l[e] = logits[t * E_NUM + e];
    int i0 = 0;
#pragma unroll
    for (int e = 1; e < E_NUM; e++)
        if (l[e] > l[i0]) i0 = e;
    int i1 = (i0 == 0) ? 1 : 0;
#pragma unroll
    for (int e = 0; e < E_NUM; e++) {
        if (e == i0 || e == i1) continue;
        if (l[e] > l[i1]) i1 = e;
    }
    float p1 = __expf(l[i1] - l[i0]);  // <= 1 since l[i0] is max
    float w0 = 1.0f / (1.0f + p1);
    float w1 = p1 / (1.0f + p1);
    topk_id[2 * t] = i0;
    topk_id[2 * t + 1] = i1;
    topk_w[2 * t] = w0;
    topk_w[2 * t + 1] = w1;
    atomicAdd(&counts[i0], 1);
    atomicAdd(&counts[i1], 1);
}

__global__ void offsets_kernel(const int* __restrict__ counts,
                               int* __restrict__ offs,
                               int* __restrict__ cursor) {
    if (threadIdx.x == 0 && blockIdx.x == 0) {
        int acc = 0;
        for (int e = 0; e < E_NUM; e++) {
            offs[e] = acc;
            cursor[e] = acc;
            acc += counts[e];
        }
        offs[E_NUM] = acc;
    }
}

__global__ void scatter_kernel(const int* __restrict__ topk_id,
                               const float* __restrict__ topk_w,
                               int* __restrict__ cursor,
                               int* __restrict__ rowtok,
                               float* __restrict__ wrow) {
    int t = blockIdx.x * blockDim.x + threadIdx.x;
    if (t >= T_TOK) return;
#pragma unroll
    for (int j = 0; j < 2; j++) {
        int e = topk_id[2 * t + j];
        int r = atomicAdd(&cursor[e], 1);
        rowtok[r] = t;
        wrow[r] = topk_w[2 * t + j];
    }
}

// ---------------- GEMM1 (bf16 inputs): h = silu(x@W1^T) * (x@W3^T) ----------------
// 128x128 tile over (rows, I), BK=32, 4 waves each 64x64, dual accumulators.
// 2-phase pipeline: double-buffered LDS; stage tile t+1 async while computing
// tile t; single vmcnt(0)+barrier per K-step (the __syncthreads at loop end).

__global__ __launch_bounds__(256, 3) void gemm1_bf16_kernel(
    const bf16* __restrict__ xb, const bf16* __restrict__ wptr,
    long long wstride, int e_base,
    const int* __restrict__ offs, const int* __restrict__ rowtok,
    bf16* __restrict__ h) {
    const int ei = blockIdx.y >> 6;
    const int e = e_base + ei;
    const int tm = blockIdx.y & 63;
    const int mBeg = offs[e], mEnd = offs[e + 1];
    const int m0 = mBeg + tm * 128;
    if (m0 >= mEnd) return;
    const int n0 = blockIdx.x * 128;

    __shared__ alignas(16) bf16 As[2][128 * 32];
    __shared__ alignas(16) bf16 Bg[2][128 * 32];
    __shared__ alignas(16) bf16 Bu[2][128 * 32];

    const int tid = threadIdx.x;
    const int lane = tid & 63;
    const int wv = tid >> 6;
    const int wr = wv >> 1, wc = wv & 1;

    // chunk c in [0,512): covers 8 elems of [128][32] tile; row=c>>2, ks=(c&3)*8
    const int c0 = tid, c1 = tid + 256;
    const int ar0 = c0 >> 2, ks0 = (c0 & 3) * 8;
    const int ar1 = c1 >> 2, ks1 = (c1 & 3) * 8;
    const bf16* aG0 = xb + (size_t)rowtok[min(m0 + ar0, R_TOT - 1)] * H_DIM + ks0;
    const bf16* aG1 = xb + (size_t)rowtok[min(m0 + ar1, R_TOT - 1)] * H_DIM + ks1;
    const bf16* w13e = wptr + (size_t)ei * wstride;
    const bf16* bG0 = w13e + (size_t)(n0 + ar0) * H_DIM + ks0;
    const bf16* bG1 = w13e + (size_t)(n0 + ar1) * H_DIM + ks1;
    const bf16* uG0 = w13e + (size_t)(I_DIM + n0 + ar0) * H_DIM + ks0;
    const bf16* uG1 = w13e + (size_t)(I_DIM + n0 + ar1) * H_DIM + ks1;

    // wave-uniform LDS chunk element offsets (HW writes base + lane*16B)
    const int wb8 = (wv * 64) * 8;
    const int wb8b = (wv * 64 + 256) * 8;

#define STG1(B, KT)                          \
    gl_lds16(aG0 + (KT), &As[B][wb8]);       \
    gl_lds16(aG1 + (KT), &As[B][wb8b]);      \
    gl_lds16(bG0 + (KT), &Bg[B][wb8]);       \
    gl_lds16(bG1 + (KT), &Bg[B][wb8b]);      \
    gl_lds16(uG0 + (KT), &Bu[B][wb8]);       \
    gl_lds16(uG1 + (KT), &Bu[B][wb8b]);

    floatx4 accG[4][4] = {};
    floatx4 accU[4][4] = {};

    const int lr = lane & 15;
    const int kg = lane >> 4;

    // prologue: stage first tile, drain, barrier
    STG1(0, 0);
    __syncthreads();

    int cur = 0;
    for (int kt = 0; kt < H_DIM; kt += 32) {
        // issue next-tile async loads into the other buffer (in flight across compute)
        if (kt + 32 < H_DIM) { STG1(cur ^ 1, kt + 32); }

        short8 af[4], bgf[4], buf2[4];
#pragma unroll
        for (int i = 0; i < 4; i++)
            af[i] = *(const short8*)(&As[cur][(wr * 64 + i * 16 + lr) * 32 + kg * 8]);
#pragma unroll
        for (int j = 0; j < 4; j++) {
            bgf[j] = *(const short8*)(&Bg[cur][(wc * 64 + j * 16 + lr) * 32 + kg * 8]);
            buf2[j] = *(const short8*)(&Bu[cur][(wc * 64 + j * 16 + lr) * 32 + kg * 8]);
        }
#pragma unroll
        for (int i = 0; i < 4; i++)
#pragma unroll
            for (int j = 0; j < 4; j++) {
                accG[i][j] = __builtin_amdgcn_mfma_f32_16x16x32_bf16(af[i], bgf[j], accG[i][j], 0, 0, 0);
                accU[i][j] = __builtin_amdgcn_mfma_f32_16x16x32_bf16(af[i], buf2[j], accU[i][j], 0, 0, 0);
            }
        __syncthreads();  // waits prefetch (vmcnt0) + all lds reads, then barrier
        cur ^= 1;
    }
#undef STG1

    // epilogue: silu(g)*u -> h (C/D layout: col=lane&15, row=(lane>>4)*4+v)
    const int quad = lane >> 4;
#pragma unroll
    for (int i = 0; i < 4; i++) {
        const int grb = m0 + wr * 64 + i * 16 + quad * 4;
#pragma unroll
        for (int j = 0; j < 4; j++) {
            const int gc = n0 + wc * 64 + j * 16 + lr;
#pragma unroll
            for (int v = 0; v < 4; v++) {
                const int gr = grb + v;
                if (gr < mEnd) {
                    float g = accG[i][j][v];
                    float u = accU[i][j][v];
                    float s = g / (1.0f + __expf(-g));
                    h[(size_t)gr * I_DIM + gc] = __float2bfloat16(s * u);
                }
            }
        }
    }
}

// ---------------- GEMM2 (bf16 inputs): out[tok] += wrow * (h @ W2^T) ----------------

__global__ __launch_bounds__(256, 3) void gemm2_bf16_kernel(
    const bf16* __restrict__ hbuf, const bf16* __restrict__ wptr,
    long long wstride, int e_base,
    const int* __restrict__ offs, const int* __restrict__ rowtok,
    const float* __restrict__ wrow, float* __restrict__ out) {
    const int ei = blockIdx.y >> 6;
    const int e = e_base + ei;
    const int tm = blockIdx.y & 63;
    const int mBeg = offs[e], mEnd = offs[e + 1];
    const int m0 = mBeg + tm * 128;
    if (m0 >= mEnd) return;
    const int n0 = blockIdx.x * 128;

    __shared__ alignas(16) bf16 As[2][128 * 32];
    __shared__ alignas(16) bf16 Bs[2][128 * 32];

    const int tid = threadIdx.x;
    const int lane = tid & 63;
    const int wv = tid >> 6;
    const int wr = wv >> 1, wc = wv & 1;

    const int c0 = tid, c1 = tid + 256;
    const int ar0 = c0 >> 2, ks0 = (c0 & 3) * 8;
    const int ar1 = c1 >> 2, ks1 = (c1 & 3) * 8;
    const bf16* aG0 = hbuf + (size_t)min(m0 + ar0, R_TOT - 1) * I_DIM + ks0;
    const bf16* aG1 = hbuf + (size_t)min(m0 + ar1, R_TOT - 1) * I_DIM + ks1;
    const bf16* w2e = wptr + (size_t)ei * wstride;
    const bf16* bG0 = w2e + (size_t)(n0 + ar0) * I_DIM + ks0;
    const bf16* bG1 = w2e + (size_t)(n0 + ar1) * I_DIM + ks1;

    const int wb8 = (wv * 64) * 8;
    const int wb8b = (wv * 64 + 256) * 8;

#define STG2(B, KT)                          \
    gl_lds16(aG0 + (KT), &As[B][wb8]);       \
    gl_lds16(aG1 + (KT), &As[B][wb8b]);      \
    gl_lds16(bG0 + (KT), &Bs[B][wb8]);       \
    gl_lds16(bG1 + (KT), &Bs[B][wb8b]);

    floatx4 acc[4][4] = {};
    const int lr = lane & 15;
    const int kg = lane >> 4;

    STG2(0, 0);
    __syncthreads();

    int cur = 0;
    for (int kt = 0; kt < I_DIM; kt += 32) {
        if (kt + 32 < I_DIM) { STG2(cur ^ 1, kt + 32); }

        short8 af[4], bf_[4];
#pragma unroll
        for (int i = 0; i < 4; i++)
            af[i] = *(const short8*)(&As[cur][(wr * 64 + i * 16 + lr) * 32 + kg * 8]);
#pragma unroll
        for (int j = 0; j < 4; j++)
            bf_[j] = *(const short8*)(&Bs[cur][(wc * 64 + j * 16 + lr) * 32 + kg * 8]);
#pragma unroll
        for (int i = 0; i < 4; i++)
#pragma unroll
            for (int j = 0; j < 4; j++)
                acc[i][j] = __builtin_amdgcn_mfma_f32_16x16x32_bf16(af[i], bf_[j], acc[i][j], 0, 0, 0);
        __syncthreads();
        cur ^= 1;
    }
#undef STG2

    const int quad = lane >> 4;
#pragma unroll
    for (int i = 0; i < 4; i++) {
        const int grb = m0 + wr * 64 + i * 16 + quad * 4;
#pragma unroll
        for (int j = 0; j < 4; j++) {
            const int gc = n0 + wc * 64 + j * 16 + lr;
#pragma unroll
            for (int v = 0; v < 4; v++) {
                const int gr = grb + v;
                if (gr < mEnd) {
                    const int t = rowtok[gr];
                    atomicAdd(&out[(size_t)t * H_DIM + gc], wrow[gr] * acc[i][j][v]);
                }
            }
        }
    }
}

// ---------------- fallback GEMMs (fp32 inputs, verified) ----------------

__global__ __launch_bounds__(256) void gemm1_f32_kernel(
    const float* __restrict__ x, const float* __restrict__ w13,
    const int* __restrict__ offs, const int* __restrict__ rowtok,
    bf16* __restrict__ h) {
    const int e = blockIdx.y >> 6;
    const int tm = blockIdx.y & 63;
    const int mBeg = offs[e], mEnd = offs[e + 1];
    const int m0 = mBeg + tm * 128;
    if (m0 >= mEnd) return;
    const int n0 = blockIdx.x * 128;

    __shared__ alignas(16) bf16 As[128 * 32];
    __shared__ alignas(16) bf16 Bg[128 * 32];
    __shared__ alignas(16) bf16 Bu[128 * 32];

    const int tid = threadIdx.x;
    const int lane = tid & 63;
    const int wv = tid >> 6;
    const int wr = wv >> 1, wc = wv & 1;

    const int c0 = tid, c1 = tid + 256;
    const int ar0 = c0 >> 2, ks0 = (c0 & 3) * 8;
    const int ar1 = c1 >> 2, ks1 = (c1 & 3) * 8;
    const int rr0 = min(m0 + ar0, R_TOT - 1);
    const int rr1 = min(m0 + ar1, R_TOT - 1);
    const float* aG0 = x + (size_t)rowtok[rr0] * H_DIM + ks0;
    const float* aG1 = x + (size_t)rowtok[rr1] * H_DIM + ks1;
    const float* w13e = w13 + (size_t)e * (2 * I_DIM) * H_DIM;
    const float* bG0 = w13e + (size_t)(n0 + ar0) * H_DIM + ks0;
    const float* bG1 = w13e + (size_t)(n0 + ar1) * H_DIM + ks1;
    const float* uG0 = w13e + (size_t)(I_DIM + n0 + ar0) * H_DIM + ks0;
    const float* uG1 = w13e + (size_t)(I_DIM + n0 + ar1) * H_DIM + ks1;

    floatx4 accG[4][4] = {};
    floatx4 accU[4][4] = {};

    const int lr = lane & 15;
    const int kg = lane >> 4;

    for (int kt = 0; kt < H_DIM; kt += 32) {
        short8 va0 = ld_cvt8(aG0 + kt);
        short8 va1 = ld_cvt8(aG1 + kt);
        short8 vg0 = ld_cvt8(bG0 + kt);
        short8 vg1 = ld_cvt8(bG1 + kt);
        short8 vu0 = ld_cvt8(uG0 + kt);
        short8 vu1 = ld_cvt8(uG1 + kt);
        __syncthreads();
        *(short8*)(As + c0 * 8) = va0;
        *(short8*)(As + c1 * 8) = va1;
        *(short8*)(Bg + c0 * 8) = vg0;
        *(short8*)(Bg + c1 * 8) = vg1;
        *(short8*)(Bu + c0 * 8) = vu0;
        *(short8*)(Bu + c1 * 8) = vu1;
        __syncthreads();

        short8 af[4], bgf[4], buf2[4];
#pragma unroll
        for (int i = 0; i < 4; i++)
            af[i] = *(const short8*)(As + (wr * 64 + i * 16 + lr) * 32 + kg * 8);
#pragma unroll
        for (int j = 0; j < 4; j++) {
            bgf[j] = *(const short8*)(Bg + (wc * 64 + j * 16 + lr) * 32 + kg * 8);
            buf2[j] = *(const short8*)(Bu + (wc * 64 + j * 16 + lr) * 32 + kg * 8);
        }
#pragma unroll
        for (int i = 0; i < 4; i++)
#pragma unroll
            for (int j = 0; j < 4; j++) {
                accG[i][j] = __builtin_amdgcn_mfma_f32_16x16x32_bf16(af[i], bgf[j], accG[i][j], 0, 0, 0);
                accU[i][j] = __builtin_amdgcn_mfma_f32_16x16x32_bf16(af[i], buf2[j], accU[i][j], 0, 0, 0);
            }
    }

    const int quad = lane >> 4;
#pragma unroll
    for (int i = 0; i < 4; i++) {
        const int grb = m0 + wr * 64 + i * 16 + quad * 4;
#pragma unroll
        for (int j = 0; j < 4; j++) {
            const int gc = n0 + wc * 64 + j * 16 + lr;
#pragma unroll
            for (int v = 0; v < 4; v++) {
                const int gr = grb + v;
                if (gr < mEnd) {
                    float g = accG[i][j][v];
                    float u = accU[i][j][v];
                    float s = g / (1.0f + __expf(-g));
                    h[(size_t)gr * I_DIM + gc] = __float2bfloat16(s * u);
                }
            }
        }
    }
}

__global__ __launch_bounds__(256) void gemm2_f32_kernel(
    const bf16* __restrict__ hbuf, const float* __restrict__ w2,
    const int* __restrict__ offs, const int* __restrict__ rowtok,
    const float* __restrict__ wrow, float* __restrict__ out) {
    const int e = blockIdx.y >> 6;
    const int tm = blockIdx.y & 63;
    const int mBeg = offs[e], mEnd = offs[e + 1];
    const int m0 = mBeg + tm * 128;
    if (m0 >= mEnd) return;
    const int n0 = blockIdx.x * 128;

    __shared__ alignas(16) bf16 As[128 * 32];
    __shared__ alignas(16) bf16 Bs[128 * 32];

    const int tid = threadIdx.x;
    const int lane = tid & 63;
    const int wv = tid >> 6;
    const int wr = wv >> 1, wc = wv & 1;

    const int c0 = tid, c1 = tid + 256;
    const int ar0 = c0 >> 2, ks0 = (c0 & 3) * 8;
    const int ar1 = c1 >> 2, ks1 = (c1 & 3) * 8;
    const bf16* aG0 = hbuf + (size_t)min(m0 + ar0, R_TOT - 1) * I_DIM + ks0;
    const bf16* aG1 = hbuf + (size_t)min(m0 + ar1, R_TOT - 1) * I_DIM + ks1;
    const float* w2e = w2 + (size_t)e * H_DIM * I_DIM;
    const float* bG0 = w2e + (size_t)(n0 + ar0) * I_DIM + ks0;
    const float* bG1 = w2e + (size_t)(n0 + ar1) * I_DIM + ks1;

    floatx4 acc[4][4] = {};
    const int lr = lane & 15;
    const int kg = lane >> 4;

    for (int kt = 0; kt < I_DIM; kt += 32) {
        short8 va0 = *(const short8*)(aG0 + kt);
        short8 va1 = *(const short8*)(aG1 + kt);
        short8 vb0 = ld_cvt8(bG0 + kt);
        short8 vb1 = ld_cvt8(bG1 + kt);
        __syncthreads();
        *(short8*)(As + c0 * 8) = va0;
        *(short8*)(As + c1 * 8) = va1;
        *(short8*)(Bs + c0 * 8) = vb0;
        *(short8*)(Bs + c1 * 8) = vb1;
        __syncthreads();

        short8 af[4], bf_[4];
#pragma unroll
        for (int i = 0; i < 4; i++)
            af[i] = *(const short8*)(As + (wr * 64 + i * 16 + lr) * 32 + kg * 8);
#pragma unroll
        for (int j = 0; j < 4; j++)
            bf_[j] = *(const short8*)(Bs + (wc * 64 + j * 16 + lr) * 32 + kg * 8);
#pragma unroll
        for (int i = 0; i < 4; i++)
#pragma unroll
            for (int j = 0; j < 4; j++)
                acc[i][j] = __builtin_amdgcn_mfma_f32_16x16x32_bf16(af[i], bf_[j], acc[i][j], 0, 0, 0);
    }

    const int quad = lane >> 4;
#pragma unroll
    for (int i = 0; i < 4; i++) {
        const int grb = m0 + wr * 64 + i * 16 + quad * 4;
#pragma unroll
        for (int j = 0; j < 4; j++) {
            const int gc = n0 + wc * 64 + j * 16 + lr;
#pragma unroll
            for (int v = 0; v < 4; v++) {
                const int gr = grb + v;
                if (gr < mEnd) {
                    const int t = rowtok[gr];
                    atomicAdd(&out[(size_t)t * H_DIM + gc], wrow[gr] * acc[i][j][v]);
                }
            }
        }
    }
}

// ---------------- launch ----------------

extern "C" void kernel_launch(void* const* d_in, const int* in_sizes, int n_in,
                              void* d_out, int out_size, void* d_ws, size_t ws_size,
                              hipStream_t stream) {
    const float* x = (const float*)d_in[0];
    const float* rl = (const float*)d_in[1];
    const float* w13 = (const float*)d_in[2];
    const float* w2 = (const float*)d_in[3];
    float* out = (float*)d_out;

    char* ws = (char*)d_ws;
    int* counts = (int*)(ws);                       // 8 ints
    int* offs = (int*)(ws + 256);                   // 9 ints
    int* cursor = (int*)(ws + 512);                 // 8 ints
    int* topk_id = (int*)(ws + 1024);               // 2*T ints   = 65536 B
    float* topk_w = (float*)(ws + 1024 + 65536);    // 2*T floats = 65536 B
    int* rowtok = (int*)(ws + 1024 + 2 * 65536);    // R ints     = 65536 B
    float* wrow = (float*)(ws + 1024 + 3 * 65536);  // R floats   = 65536 B

    const size_t BASE = 1024 + 4 * 65536;                       // 263,168
    const size_t H_BYTES = (size_t)R_TOT * I_DIM * 2;           // 92,274,688
    const size_t XB_BYTES = (size_t)T_TOK * H_DIM * 2;          // 16,777,216
    const size_t W13_BYTES = (size_t)E_NUM * 2 * I_DIM * H_DIM * 2;  // 92,274,688
    const size_t W13_SLICE = (size_t)2 * I_DIM * H_DIM * 2;     // 11,534,336
    const size_t W2_SLICE = (size_t)H_DIM * I_DIM * 2;          // 5,767,168

    bf16* h = (bf16*)(ws + BASE);
    bf16* xb = (bf16*)(ws + BASE + H_BYTES);
    bf16* wbuf = (bf16*)(ws + BASE + H_BYTES + XB_BYTES);  // w13b, later reused for w2b

    const size_t NEED_BULK = BASE + H_BYTES + XB_BYTES + W13_BYTES;   // ~202 MB
    const size_t NEED_SLICE = BASE + H_BYTES + XB_BYTES + W13_SLICE;  // ~121 MB

    // ---- routing (common) ----
    zero_out_kernel<<<(T_TOK * H_DIM) / (256 * 4), 256, 0, stream>>>(out);
    zero_counts_kernel<<<1, 64, 0, stream>>>(counts);
    router_kernel<<<(T_TOK + 255) / 256, 256, 0, stream>>>(rl, topk_id, topk_w, counts);
    offsets_kernel<<<1, 64, 0, stream>>>(counts, offs, cursor);
    scatter_kernel<<<(T_TOK + 255) / 256, 256, 0, stream>>>(topk_id, topk_w, cursor, rowtok, wrow);

    if (ws_size >= NEED_BULK) {
        // bulk pre-convert; w2b aliased into the w13b region after gemm1
        cvt_bf16_kernel<<<2048, 256, 0, stream>>>(x, xb, (T_TOK * H_DIM) / 8);
        cvt_bf16_kernel<<<2048, 256, 0, stream>>>(w13, wbuf, (int)(W13_BYTES / 2 / 8));
        gemm1_bf16_kernel<<<dim3(I_DIM / 128, E_NUM * 64), 256, 0, stream>>>(
            xb, wbuf, (long long)2 * I_DIM * H_DIM, 0, offs, rowtok, h);
        cvt_bf16_kernel<<<2048, 256, 0, stream>>>(w2, wbuf, (E_NUM * H_DIM * I_DIM) / 8);
        gemm2_bf16_kernel<<<dim3(H_DIM / 128, E_NUM * 64), 256, 0, stream>>>(
            h, wbuf, (long long)H_DIM * I_DIM, 0, offs, rowtok, wrow, out);
    } else if (ws_size >= NEED_SLICE) {
        // per-expert slice conversion into a single small buffer (stream-serial WAR safe)
        cvt_bf16_kernel<<<2048, 256, 0, stream>>>(x, xb, (T_TOK * H_DIM) / 8);
        for (int e = 0; e < E_NUM; e++) {
            cvt_bf16_kernel<<<1024, 256, 0, stream>>>(
                w13 + (size_t)e * 2 * I_DIM * H_DIM, wbuf, (int)(W13_SLICE / 2 / 8));
            gemm1_bf16_kernel<<<dim3(I_DIM / 128, 64), 256, 0, stream>>>(
                xb, wbuf, 0LL, e, offs, rowtok, h);
        }
        for (int e = 0; e < E_NUM; e++) {
            cvt_bf16_kernel<<<1024, 256, 0, stream>>>(
                w2 + (size_t)e * H_DIM * I_DIM, wbuf, (int)(W2_SLICE / 2 / 8));
            gemm2_bf16_kernel<<<dim3(H_DIM / 128, 64), 256, 0, stream>>>(
                h, wbuf, 0LL, e, offs, rowtok, wrow, out);
        }
    } else {
        // verified fallback: fp32-staging GEMMs (uses only BASE + h)
        gemm1_f32_kernel<<<dim3(I_DIM / 128, E_NUM * 64), 256, 0, stream>>>(
            x, w13, offs, rowtok, h);
        gemm2_f32_kernel<<<dim3(H_DIM / 128, E_NUM * 64), 256, 0, stream>>>(
            h, w2, offs, rowtok, wrow, out);
    }
}

// Round 4
// 1179.615 us; speedup vs baseline: 1.5647x; 1.5647x over previous
//
#include <hip/hip_runtime.h>
#include <hip/hip_bf16.h>

#define T_TOK 8192
#define H_DIM 1024
#define I_DIM 2816
#define E_NUM 8
#define R_TOT (2 * T_TOK)

typedef __hip_bfloat16 bf16;
typedef __attribute__((ext_vector_type(8))) short short8;
typedef __attribute__((ext_vector_type(4))) float floatx4;

__device__ inline unsigned short f2b(float f) {
    bf16 b = __float2bfloat16(f);
    unsigned short u;
    __builtin_memcpy(&u, &b, 2);
    return u;
}

// load 8 consecutive fp32, round to bf16, pack as short8 (4 VGPRs)
__device__ inline short8 ld_cvt8(const float* p) {
    float4 f0 = *(const float4*)p;
    float4 f1 = *(const float4*)(p + 4);
    short8 r;
    r[0] = (short)f2b(f0.x); r[1] = (short)f2b(f0.y);
    r[2] = (short)f2b(f0.z); r[3] = (short)f2b(f0.w);
    r[4] = (short)f2b(f1.x); r[5] = (short)f2b(f1.y);
    r[6] = (short)f2b(f1.z); r[7] = (short)f2b(f1.w);
    return r;
}

// async global(bf16, 16B-aligned) -> LDS, 16 bytes per lane.
// LDS dest is wave-uniform base + lane*16 (pass the wave's chunk base).
__device__ inline void gl_lds16(const void* g, void* l) {
    __builtin_amdgcn_global_load_lds(
        (const __attribute__((address_space(1))) void*)g,
        (__attribute__((address_space(3))) void*)l, 16, 0, 0);
}

// ---------------- fp32 -> bf16 pre-conversion (memory-bound) ----------------

__global__ __launch_bounds__(256) void cvt_bf16_kernel(const float* __restrict__ in,
                                                       bf16* __restrict__ out, int n8) {
    int stride = gridDim.x * blockDim.x;
    for (int i = blockIdx.x * blockDim.x + threadIdx.x; i < n8; i += stride) {
        short8 v = ld_cvt8(in + (size_t)i * 8);
        *(short8*)(out + (size_t)i * 8) = v;
    }
}

// ---------------- routing ----------------

__global__ void zero_counts_kernel(int* counts) {
    if (threadIdx.x < E_NUM) counts[threadIdx.x] = 0;
}

__global__ void zero_out_kernel(float* __restrict__ out) {
    size_t i = ((size_t)blockIdx.x * 256 + threadIdx.x) * 4;
    float4 z = {0.0f, 0.0f, 0.0f, 0.0f};
    *(float4*)(out + i) = z;
}

__global__ void router_kernel(const float* __restrict__ logits,
                              int* __restrict__ topk_id,
                              float* __restrict__ topk_w,
                              int* __restrict__ counts) {
    int t = blockIdx.x * blockDim.x + threadIdx.x;
    if (t >= T_TOK) return;
    float l[E_NUM];
#pragma unroll
    for (int e = 0; e < E_NUM; e++) l[e] = logits[t * E_NUM + e];
    int i0 = 0;
#pragma unroll
    for (int e = 1; e < E_NUM; e++)
        if (l[e] > l[i0]) i0 = e;
    int i1 = (i0 == 0) ? 1 : 0;
#pragma unroll
    for (int e = 0; e < E_NUM; e++) {
        if (e == i0 || e == i1) continue;
        if (l[e] > l[i1]) i1 = e;
    }
    float p1 = __expf(l[i1] - l[i0]);  // <= 1 since l[i0] is max
    float w0 = 1.0f / (1.0f + p1);
    float w1 = p1 / (1.0f + p1);
    topk_id[2 * t] = i0;
    topk_id[2 * t + 1] = i1;
    topk_w[2 * t] = w0;
    topk_w[2 * t + 1] = w1;
    atomicAdd(&counts[i0], 1);
    atomicAdd(&counts[i1], 1);
}

__global__ void offsets_kernel(const int* __restrict__ counts,
                               int* __restrict__ offs,
                               int* __restrict__ cursor) {
    if (threadIdx.x == 0 && blockIdx.x == 0) {
        int acc = 0;
        for (int e = 0; e < E_NUM; e++) {
            offs[e] = acc;
            cursor[e] = acc;
            acc += counts[e];
        }
        offs[E_NUM] = acc;
    }
}

__global__ void scatter_kernel(const int* __restrict__ topk_id,
                               const float* __restrict__ topk_w,
                               int* __restrict__ cursor,
                               int* __restrict__ rowtok,
                               float* __restrict__ wrow) {
    int t = blockIdx.x * blockDim.x + threadIdx.x;
    if (t >= T_TOK) return;
#pragma unroll
    for (int j = 0; j < 2; j++) {
        int e = topk_id[2 * t + j];
        int r = atomicAdd(&cursor[e], 1);
        rowtok[r] = t;
        wrow[r] = topk_w[2 * t + j];
    }
}

// ---------------- GEMM1 (bf16 inputs): h = silu(x@W1^T) * (x@W3^T) ----------------
// 128x128 tile over (rows, I), BK=32, 4 waves each 64x64, dual accumulators.
// 2-phase pipeline: double-buffered LDS; stage tile t+1 async while computing
// tile t; single vmcnt(0)+barrier per K-step. NOTE: plain __launch_bounds__(256)
// -- a min-waves arg of 3 forced VGPR=84 and spilled the 128-VGPR accumulator
// set to scratch (round 3: WRITE_SIZE 9e4->2.7e6 KB, dur 488->1127 us).

__global__ __launch_bounds__(256) void gemm1_bf16_kernel(
    const bf16* __restrict__ xb, const bf16* __restrict__ wptr,
    long long wstride, int e_base,
    const int* __restrict__ offs, const int* __restrict__ rowtok,
    bf16* __restrict__ h) {
    const int ei = blockIdx.y >> 6;
    const int e = e_base + ei;
    const int tm = blockIdx.y & 63;
    const int mBeg = offs[e], mEnd = offs[e + 1];
    const int m0 = mBeg + tm * 128;
    if (m0 >= mEnd) return;
    const int n0 = blockIdx.x * 128;

    __shared__ alignas(16) bf16 As[2][128 * 32];
    __shared__ alignas(16) bf16 Bg[2][128 * 32];
    __shared__ alignas(16) bf16 Bu[2][128 * 32];

    const int tid = threadIdx.x;
    const int lane = tid & 63;
    const int wv = tid >> 6;
    const int wr = wv >> 1, wc = wv & 1;

    // chunk c in [0,512): covers 8 elems of [128][32] tile; row=c>>2, ks=(c&3)*8
    const int c0 = tid, c1 = tid + 256;
    const int ar0 = c0 >> 2, ks0 = (c0 & 3) * 8;
    const int ar1 = c1 >> 2, ks1 = (c1 & 3) * 8;
    const bf16* aG0 = xb + (size_t)rowtok[min(m0 + ar0, R_TOT - 1)] * H_DIM + ks0;
    const bf16* aG1 = xb + (size_t)rowtok[min(m0 + ar1, R_TOT - 1)] * H_DIM + ks1;
    const bf16* w13e = wptr + (size_t)ei * wstride;
    const bf16* bG0 = w13e + (size_t)(n0 + ar0) * H_DIM + ks0;
    const bf16* bG1 = w13e + (size_t)(n0 + ar1) * H_DIM + ks1;
    const bf16* uG0 = w13e + (size_t)(I_DIM + n0 + ar0) * H_DIM + ks0;
    const bf16* uG1 = w13e + (size_t)(I_DIM + n0 + ar1) * H_DIM + ks1;

    // wave-uniform LDS chunk element offsets (HW writes base + lane*16B)
    const int wb8 = (wv * 64) * 8;
    const int wb8b = (wv * 64 + 256) * 8;

#define STG1(B, KT)                          \
    gl_lds16(aG0 + (KT), &As[B][wb8]);       \
    gl_lds16(aG1 + (KT), &As[B][wb8b]);      \
    gl_lds16(bG0 + (KT), &Bg[B][wb8]);       \
    gl_lds16(bG1 + (KT), &Bg[B][wb8b]);      \
    gl_lds16(uG0 + (KT), &Bu[B][wb8]);       \
    gl_lds16(uG1 + (KT), &Bu[B][wb8b]);

    floatx4 accG[4][4] = {};
    floatx4 accU[4][4] = {};

    const int lr = lane & 15;
    const int kg = lane >> 4;

    // prologue: stage first tile, drain, barrier
    STG1(0, 0);
    __syncthreads();

    int cur = 0;
    for (int kt = 0; kt < H_DIM; kt += 32) {
        // issue next-tile async loads into the other buffer (in flight across compute)
        if (kt + 32 < H_DIM) { STG1(cur ^ 1, kt + 32); }

        short8 af[4], bgf[4], buf2[4];
#pragma unroll
        for (int i = 0; i < 4; i++)
            af[i] = *(const short8*)(&As[cur][(wr * 64 + i * 16 + lr) * 32 + kg * 8]);
#pragma unroll
        for (int j = 0; j < 4; j++) {
            bgf[j] = *(const short8*)(&Bg[cur][(wc * 64 + j * 16 + lr) * 32 + kg * 8]);
            buf2[j] = *(const short8*)(&Bu[cur][(wc * 64 + j * 16 + lr) * 32 + kg * 8]);
        }
#pragma unroll
        for (int i = 0; i < 4; i++)
#pragma unroll
            for (int j = 0; j < 4; j++) {
                accG[i][j] = __builtin_amdgcn_mfma_f32_16x16x32_bf16(af[i], bgf[j], accG[i][j], 0, 0, 0);
                accU[i][j] = __builtin_amdgcn_mfma_f32_16x16x32_bf16(af[i], buf2[j], accU[i][j], 0, 0, 0);
            }
        __syncthreads();  // waits prefetch (vmcnt0) + all lds reads, then barrier
        cur ^= 1;
    }
#undef STG1

    // epilogue: silu(g)*u -> h (C/D layout: col=lane&15, row=(lane>>4)*4+v)
    const int quad = lane >> 4;
#pragma unroll
    for (int i = 0; i < 4; i++) {
        const int grb = m0 + wr * 64 + i * 16 + quad * 4;
#pragma unroll
        for (int j = 0; j < 4; j++) {
            const int gc = n0 + wc * 64 + j * 16 + lr;
#pragma unroll
            for (int v = 0; v < 4; v++) {
                const int gr = grb + v;
                if (gr < mEnd) {
                    float g = accG[i][j][v];
                    float u = accU[i][j][v];
                    float s = g / (1.0f + __expf(-g));
                    h[(size_t)gr * I_DIM + gc] = __float2bfloat16(s * u);
                }
            }
        }
    }
}

// ---------------- GEMM2 (bf16 inputs): out[tok] += wrow * (h @ W2^T) ----------------

__global__ __launch_bounds__(256) void gemm2_bf16_kernel(
    const bf16* __restrict__ hbuf, const bf16* __restrict__ wptr,
    long long wstride, int e_base,
    const int* __restrict__ offs, const int* __restrict__ rowtok,
    const float* __restrict__ wrow, float* __restrict__ out) {
    const int ei = blockIdx.y >> 6;
    const int e = e_base + ei;
    const int tm = blockIdx.y & 63;
    const int mBeg = offs[e], mEnd = offs[e + 1];
    const int m0 = mBeg + tm * 128;
    if (m0 >= mEnd) return;
    const int n0 = blockIdx.x * 128;

    __shared__ alignas(16) bf16 As[2][128 * 32];
    __shared__ alignas(16) bf16 Bs[2][128 * 32];

    const int tid = threadIdx.x;
    const int lane = tid & 63;
    const int wv = tid >> 6;
    const int wr = wv >> 1, wc = wv & 1;

    const int c0 = tid, c1 = tid + 256;
    const int ar0 = c0 >> 2, ks0 = (c0 & 3) * 8;
    const int ar1 = c1 >> 2, ks1 = (c1 & 3) * 8;
    const bf16* aG0 = hbuf + (size_t)min(m0 + ar0, R_TOT - 1) * I_DIM + ks0;
    const bf16* aG1 = hbuf + (size_t)min(m0 + ar1, R_TOT - 1) * I_DIM + ks1;
    const bf16* w2e = wptr + (size_t)ei * wstride;
    const bf16* bG0 = w2e + (size_t)(n0 + ar0) * I_DIM + ks0;
    const bf16* bG1 = w2e + (size_t)(n0 + ar1) * I_DIM + ks1;

    const int wb8 = (wv * 64) * 8;
    const int wb8b = (wv * 64 + 256) * 8;

#define STG2(B, KT)                          \
    gl_lds16(aG0 + (KT), &As[B][wb8]);       \
    gl_lds16(aG1 + (KT), &As[B][wb8b]);      \
    gl_lds16(bG0 + (KT), &Bs[B][wb8]);       \
    gl_lds16(bG1 + (KT), &Bs[B][wb8b]);

    floatx4 acc[4][4] = {};
    const int lr = lane & 15;
    const int kg = lane >> 4;

    STG2(0, 0);
    __syncthreads();

    int cur = 0;
    for (int kt = 0; kt < I_DIM; kt += 32) {
        if (kt + 32 < I_DIM) { STG2(cur ^ 1, kt + 32); }

        short8 af[4], bf_[4];
#pragma unroll
        for (int i = 0; i < 4; i++)
            af[i] = *(const short8*)(&As[cur][(wr * 64 + i * 16 + lr) * 32 + kg * 8]);
#pragma unroll
        for (int j = 0; j < 4; j++)
            bf_[j] = *(const short8*)(&Bs[cur][(wc * 64 + j * 16 + lr) * 32 + kg * 8]);
#pragma unroll
        for (int i = 0; i < 4; i++)
#pragma unroll
            for (int j = 0; j < 4; j++)
                acc[i][j] = __builtin_amdgcn_mfma_f32_16x16x32_bf16(af[i], bf_[j], acc[i][j], 0, 0, 0);
        __syncthreads();
        cur ^= 1;
    }
#undef STG2

    const int quad = lane >> 4;
#pragma unroll
    for (int i = 0; i < 4; i++) {
        const int grb = m0 + wr * 64 + i * 16 + quad * 4;
#pragma unroll
        for (int j = 0; j < 4; j++) {
            const int gc = n0 + wc * 64 + j * 16 + lr;
#pragma unroll
            for (int v = 0; v < 4; v++) {
                const int gr = grb + v;
                if (gr < mEnd) {
                    const int t = rowtok[gr];
                    atomicAdd(&out[(size_t)t * H_DIM + gc], wrow[gr] * acc[i][j][v]);
                }
            }
        }
    }
}

// ---------------- fallback GEMMs (fp32 inputs, verified) ----------------

__global__ __launch_bounds__(256) void gemm1_f32_kernel(
    const float* __restrict__ x, const float* __restrict__ w13,
    const int* __restrict__ offs, const int* __restrict__ rowtok,
    bf16* __restrict__ h) {
    const int e = blockIdx.y >> 6;
    const int tm = blockIdx.y & 63;
    const int mBeg = offs[e], mEnd = offs[e + 1];
    const int m0 = mBeg + tm * 128;
    if (m0 >= mEnd) return;
    const int n0 = blockIdx.x * 128;

    __shared__ alignas(16) bf16 As[128 * 32];
    __shared__ alignas(16) bf16 Bg[128 * 32];
    __shared__ alignas(16) bf16 Bu[128 * 32];

    const int tid = threadIdx.x;
    const int lane = tid & 63;
    const int wv = tid >> 6;
    const int wr = wv >> 1, wc = wv & 1;

    const int c0 = tid, c1 = tid + 256;
    const int ar0 = c0 >> 2, ks0 = (c0 & 3) * 8;
    const int ar1 = c1 >> 2, ks1 = (c1 & 3) * 8;
    const int rr0 = min(m0 + ar0, R_TOT - 1);
    const int rr1 = min(m0 + ar1, R_TOT - 1);
    const float* aG0 = x + (size_t)rowtok[rr0] * H_DIM + ks0;
    const float* aG1 = x + (size_t)rowtok[rr1] * H_DIM + ks1;
    const float* w13e = w13 + (size_t)e * (2 * I_DIM) * H_DIM;
    const float* bG0 = w13e + (size_t)(n0 + ar0) * H_DIM + ks0;
    const float* bG1 = w13e + (size_t)(n0 + ar1) * H_DIM + ks1;
    const float* uG0 = w13e + (size_t)(I_DIM + n0 + ar0) * H_DIM + ks0;
    const float* uG1 = w13e + (size_t)(I_DIM + n0 + ar1) * H_DIM + ks1;

    floatx4 accG[4][4] = {};
    floatx4 accU[4][4] = {};

    const int lr = lane & 15;
    const int kg = lane >> 4;

    for (int kt = 0; kt < H_DIM; kt += 32) {
        short8 va0 = ld_cvt8(aG0 + kt);
        short8 va1 = ld_cvt8(aG1 + kt);
        short8 vg0 = ld_cvt8(bG0 + kt);
        short8 vg1 = ld_cvt8(bG1 + kt);
        short8 vu0 = ld_cvt8(uG0 + kt);
        short8 vu1 = ld_cvt8(uG1 + kt);
        __syncthreads();
        *(short8*)(As + c0 * 8) = va0;
        *(short8*)(As + c1 * 8) = va1;
        *(short8*)(Bg + c0 * 8) = vg0;
        *(short8*)(Bg + c1 * 8) = vg1;
        *(short8*)(Bu + c0 * 8) = vu0;
        *(short8*)(Bu + c1 * 8) = vu1;
        __syncthreads();

        short8 af[4], bgf[4], buf2[4];
#pragma unroll
        for (int i = 0; i < 4; i++)
            af[i] = *(const short8*)(As + (wr * 64 + i * 16 + lr) * 32 + kg * 8);
#pragma unroll
        for (int j = 0; j < 4; j++) {
            bgf[j] = *(const short8*)(Bg + (wc * 64 + j * 16 + lr) * 32 + kg * 8);
            buf2[j] = *(const short8*)(Bu + (wc * 64 + j * 16 + lr) * 32 + kg * 8);
        }
#pragma unroll
        for (int i = 0; i < 4; i++)
#pragma unroll
            for (int j = 0; j < 4; j++) {
                accG[i][j] = __builtin_amdgcn_mfma_f32_16x16x32_bf16(af[i], bgf[j], accG[i][j], 0, 0, 0);
                accU[i][j] = __builtin_amdgcn_mfma_f32_16x16x32_bf16(af[i], buf2[j], accU[i][j], 0, 0, 0);
            }
    }

    const int quad = lane >> 4;
#pragma unroll
    for (int i = 0; i < 4; i++) {
        const int grb = m0 + wr * 64 + i * 16 + quad * 4;
#pragma unroll
        for (int j = 0; j < 4; j++) {
            const int gc = n0 + wc * 64 + j * 16 + lr;
#pragma unroll
            for (int v = 0; v < 4; v++) {
                const int gr = grb + v;
                if (gr < mEnd) {
                    float g = accG[i][j][v];
                    float u = accU[i][j][v];
                    float s = g / (1.0f + __expf(-g));
                    h[(size_t)gr * I_DIM + gc] = __float2bfloat16(s * u);
                }
            }
        }
    }
}

__global__ __launch_bounds__(256) void gemm2_f32_kernel(
    const bf16* __restrict__ hbuf, const float* __restrict__ w2,
    const int* __restrict__ offs, const int* __restrict__ rowtok,
    const float* __restrict__ wrow, float* __restrict__ out) {
    const int e = blockIdx.y >> 6;
    const int tm = blockIdx.y & 63;
    const int mBeg = offs[e], mEnd = offs[e + 1];
    const int m0 = mBeg + tm * 128;
    if (m0 >= mEnd) return;
    const int n0 = blockIdx.x * 128;

    __shared__ alignas(16) bf16 As[128 * 32];
    __shared__ alignas(16) bf16 Bs[128 * 32];

    const int tid = threadIdx.x;
    const int lane = tid & 63;
    const int wv = tid >> 6;
    const int wr = wv >> 1, wc = wv & 1;

    const int c0 = tid, c1 = tid + 256;
    const int ar0 = c0 >> 2, ks0 = (c0 & 3) * 8;
    const int ar1 = c1 >> 2, ks1 = (c1 & 3) * 8;
    const bf16* aG0 = hbuf + (size_t)min(m0 + ar0, R_TOT - 1) * I_DIM + ks0;
    const bf16* aG1 = hbuf + (size_t)min(m0 + ar1, R_TOT - 1) * I_DIM + ks1;
    const float* w2e = w2 + (size_t)e * H_DIM * I_DIM;
    const float* bG0 = w2e + (size_t)(n0 + ar0) * I_DIM + ks0;
    const float* bG1 = w2e + (size_t)(n0 + ar1) * I_DIM + ks1;

    floatx4 acc[4][4] = {};
    const int lr = lane & 15;
    const int kg = lane >> 4;

    for (int kt = 0; kt < I_DIM; kt += 32) {
        short8 va0 = *(const short8*)(aG0 + kt);
        short8 va1 = *(const short8*)(aG1 + kt);
        short8 vb0 = ld_cvt8(bG0 + kt);
        short8 vb1 = ld_cvt8(bG1 + kt);
        __syncthreads();
        *(short8*)(As + c0 * 8) = va0;
        *(short8*)(As + c1 * 8) = va1;
        *(short8*)(Bs + c0 * 8) = vb0;
        *(short8*)(Bs + c1 * 8) = vb1;
        __syncthreads();

        short8 af[4], bf_[4];
#pragma unroll
        for (int i = 0; i < 4; i++)
            af[i] = *(const short8*)(As + (wr * 64 + i * 16 + lr) * 32 + kg * 8);
#pragma unroll
        for (int j = 0; j < 4; j++)
            bf_[j] = *(const short8*)(Bs + (wc * 64 + j * 16 + lr) * 32 + kg * 8);
#pragma unroll
        for (int i = 0; i < 4; i++)
#pragma unroll
            for (int j = 0; j < 4; j++)
                acc[i][j] = __builtin_amdgcn_mfma_f32_16x16x32_bf16(af[i], bf_[j], acc[i][j], 0, 0, 0);
    }

    const int quad = lane >> 4;
#pragma unroll
    for (int i = 0; i < 4; i++) {
        const int grb = m0 + wr * 64 + i * 16 + quad * 4;
#pragma unroll
        for (int j = 0; j < 4; j++) {
            const int gc = n0 + wc * 64 + j * 16 + lr;
#pragma unroll
            for (int v = 0; v < 4; v++) {
                const int gr = grb + v;
                if (gr < mEnd) {
                    const int t = rowtok[gr];
                    atomicAdd(&out[(size_t)t * H_DIM + gc], wrow[gr] * acc[i][j][v]);
                }
            }
        }
    }
}

// ---------------- launch ----------------

extern "C" void kernel_launch(void* const* d_in, const int* in_sizes, int n_in,
                              void* d_out, int out_size, void* d_ws, size_t ws_size,
                              hipStream_t stream) {
    const float* x = (const float*)d_in[0];
    const float* rl = (const float*)d_in[1];
    const float* w13 = (const float*)d_in[2];
    const float* w2 = (const float*)d_in[3];
    float* out = (float*)d_out;

    char* ws = (char*)d_ws;
    int* counts = (int*)(ws);                       // 8 ints
    int* offs = (int*)(ws + 256);                   // 9 ints
    int* cursor = (int*)(ws + 512);                 // 8 ints
    int* topk_id = (int*)(ws + 1024);               // 2*T ints   = 65536 B
    float* topk_w = (float*)(ws + 1024 + 65536);    // 2*T floats = 65536 B
    int* rowtok = (int*)(ws + 1024 + 2 * 65536);    // R ints     = 65536 B
    float* wrow = (float*)(ws + 1024 + 3 * 65536);  // R floats   = 65536 B

    const size_t BASE = 1024 + 4 * 65536;                       // 263,168
    const size_t H_BYTES = (size_t)R_TOT * I_DIM * 2;           // 92,274,688
    const size_t XB_BYTES = (size_t)T_TOK * H_DIM * 2;          // 16,777,216
    const size_t W13_BYTES = (size_t)E_NUM * 2 * I_DIM * H_DIM * 2;  // 92,274,688
    const size_t W13_SLICE = (size_t)2 * I_DIM * H_DIM * 2;     // 11,534,336
    const size_t W2_SLICE = (size_t)H_DIM * I_DIM * 2;          // 5,767,168

    bf16* h = (bf16*)(ws + BASE);
    bf16* xb = (bf16*)(ws + BASE + H_BYTES);
    bf16* wbuf = (bf16*)(ws + BASE + H_BYTES + XB_BYTES);  // w13b, later reused for w2b

    const size_t NEED_BULK = BASE + H_BYTES + XB_BYTES + W13_BYTES;   // ~202 MB
    const size_t NEED_SLICE = BASE + H_BYTES + XB_BYTES + W13_SLICE;  // ~121 MB

    // ---- routing (common) ----
    zero_out_kernel<<<(T_TOK * H_DIM) / (256 * 4), 256, 0, stream>>>(out);
    zero_counts_kernel<<<1, 64, 0, stream>>>(counts);
    router_kernel<<<(T_TOK + 255) / 256, 256, 0, stream>>>(rl, topk_id, topk_w, counts);
    offsets_kernel<<<1, 64, 0, stream>>>(counts, offs, cursor);
    scatter_kernel<<<(T_TOK + 255) / 256, 256, 0, stream>>>(topk_id, topk_w, cursor, rowtok, wrow);

    if (ws_size >= NEED_BULK) {
        // bulk pre-convert; w2b aliased into the w13b region after gemm1
        cvt_bf16_kernel<<<2048, 256, 0, stream>>>(x, xb, (T_TOK * H_DIM) / 8);
        cvt_bf16_kernel<<<2048, 256, 0, stream>>>(w13, wbuf, (int)(W13_BYTES / 2 / 8));
        gemm1_bf16_kernel<<<dim3(I_DIM / 128, E_NUM * 64), 256, 0, stream>>>(
            xb, wbuf, (long long)2 * I_DIM * H_DIM, 0, offs, rowtok, h);
        cvt_bf16_kernel<<<2048, 256, 0, stream>>>(w2, wbuf, (E_NUM * H_DIM * I_DIM) / 8);
        gemm2_bf16_kernel<<<dim3(H_DIM / 128, E_NUM * 64), 256, 0, stream>>>(
            h, wbuf, (long long)H_DIM * I_DIM, 0, offs, rowtok, wrow, out);
    } else if (ws_size >= NEED_SLICE) {
        // per-expert slice conversion into a single small buffer (stream-serial WAR safe)
        cvt_bf16_kernel<<<2048, 256, 0, stream>>>(x, xb, (T_TOK * H_DIM) / 8);
        for (int e = 0; e < E_NUM; e++) {
            cvt_bf16_kernel<<<1024, 256, 0, stream>>>(
                w13 + (size_t)e * 2 * I_DIM * H_DIM, wbuf, (int)(W13_SLICE / 2 / 8));
            gemm1_bf16_kernel<<<dim3(I_DIM / 128, 64), 256, 0, stream>>>(
                xb, wbuf, 0LL, e, offs, rowtok, h);
        }
        for (int e = 0; e < E_NUM; e++) {
            cvt_bf16_kernel<<<1024, 256, 0, stream>>>(
                w2 + (size_t)e * H_DIM * I_DIM, wbuf, (int)(W2_SLICE / 2 / 8));
            gemm2_bf16_kernel<<<dim3(H_DIM / 128, 64), 256, 0, stream>>>(
                h, wbuf, 0LL, e, offs, rowtok, wrow, out);
        }
    } else {
        // verified fallback: fp32-staging GEMMs (uses only BASE + h)
        gemm1_f32_kernel<<<dim3(I_DIM / 128, E_NUM * 64), 256, 0, stream>>>(
            x, w13, offs, rowtok, h);
        gemm2_f32_kernel<<<dim3(H_DIM / 128, E_NUM * 64), 256, 0, stream>>>(
            h, w2, offs, rowtok, wrow, out);
    }
}

// Round 5
// 1017.969 us; speedup vs baseline: 1.8131x; 1.1588x over previous
//
#include <hip/hip_runtime.h>
#include <hip/hip_bf16.h>

#define T_TOK 8192
#define H_DIM 1024
#define I_DIM 2816
#define E_NUM 8
#define R_TOT (2 * T_TOK)

typedef __hip_bfloat16 bf16;
typedef __attribute__((ext_vector_type(8))) short short8;
typedef __attribute__((ext_vector_type(4))) float floatx4;

__device__ inline unsigned short f2b(float f) {
    bf16 b = __float2bfloat16(f);
    unsigned short u;
    __builtin_memcpy(&u, &b, 2);
    return u;
}

// load 8 consecutive fp32, round to bf16, pack as short8 (4 VGPRs)
__device__ inline short8 ld_cvt8(const float* p) {
    float4 f0 = *(const float4*)p;
    float4 f1 = *(const float4*)(p + 4);
    short8 r;
    r[0] = (short)f2b(f0.x); r[1] = (short)f2b(f0.y);
    r[2] = (short)f2b(f0.z); r[3] = (short)f2b(f0.w);
    r[4] = (short)f2b(f1.x); r[5] = (short)f2b(f1.y);
    r[6] = (short)f2b(f1.z); r[7] = (short)f2b(f1.w);
    return r;
}

// async global(bf16, 16B-aligned) -> LDS, 16 bytes per lane.
// LDS dest is wave-uniform base + lane*16 (pass the wave's chunk base).
__device__ inline void gl_lds16(const void* g, void* l) {
    __builtin_amdgcn_global_load_lds(
        (const __attribute__((address_space(1))) void*)g,
        (__attribute__((address_space(3))) void*)l, 16, 0, 0);
}

// ---------------- fp32 -> bf16 pre-conversion (memory-bound) ----------------

__global__ __launch_bounds__(256) void cvt_bf16_kernel(const float* __restrict__ in,
                                                       bf16* __restrict__ out, int n8) {
    int stride = gridDim.x * blockDim.x;
    for (int i = blockIdx.x * blockDim.x + threadIdx.x; i < n8; i += stride) {
        short8 v = ld_cvt8(in + (size_t)i * 8);
        *(short8*)(out + (size_t)i * 8) = v;
    }
}

// ---------------- routing ----------------

__global__ void zero_counts_kernel(int* counts) {
    if (threadIdx.x < E_NUM) counts[threadIdx.x] = 0;
}

__global__ void zero_out_kernel(float* __restrict__ out) {
    size_t i = ((size_t)blockIdx.x * 256 + threadIdx.x) * 4;
    float4 z = {0.0f, 0.0f, 0.0f, 0.0f};
    *(float4*)(out + i) = z;
}

__global__ void router_kernel(const float* __restrict__ logits,
                              int* __restrict__ topk_id,
                              float* __restrict__ topk_w,
                              int* __restrict__ counts) {
    int t = blockIdx.x * blockDim.x + threadIdx.x;
    if (t >= T_TOK) return;
    float l[E_NUM];
#pragma unroll
    for (int e = 0; e < E_NUM; e++) l[e] = logits[t * E_NUM + e];
    int i0 = 0;
#pragma unroll
    for (int e = 1; e < E_NUM; e++)
        if (l[e] > l[i0]) i0 = e;
    int i1 = (i0 == 0) ? 1 : 0;
#pragma unroll
    for (int e = 0; e < E_NUM; e++) {
        if (e == i0 || e == i1) continue;
        if (l[e] > l[i1]) i1 = e;
    }
    float p1 = __expf(l[i1] - l[i0]);  // <= 1 since l[i0] is max
    float w0 = 1.0f / (1.0f + p1);
    float w1 = p1 / (1.0f + p1);
    topk_id[2 * t] = i0;
    topk_id[2 * t + 1] = i1;
    topk_w[2 * t] = w0;
    topk_w[2 * t + 1] = w1;
    atomicAdd(&counts[i0], 1);
    atomicAdd(&counts[i1], 1);
}

__global__ void offsets_kernel(const int* __restrict__ counts,
                               int* __restrict__ offs,
                               int* __restrict__ cursor) {
    if (threadIdx.x == 0 && blockIdx.x == 0) {
        int acc = 0;
        for (int e = 0; e < E_NUM; e++) {
            offs[e] = acc;
            cursor[e] = acc;
            acc += counts[e];
        }
        offs[E_NUM] = acc;
    }
}

__global__ void scatter_kernel(const int* __restrict__ topk_id,
                               const float* __restrict__ topk_w,
                               int* __restrict__ cursor,
                               int* __restrict__ rowtok,
                               float* __restrict__ wrow) {
    int t = blockIdx.x * blockDim.x + threadIdx.x;
    if (t >= T_TOK) return;
#pragma unroll
    for (int j = 0; j < 2; j++) {
        int e = topk_id[2 * t + j];
        int r = atomicAdd(&cursor[e], 1);
        rowtok[r] = t;
        wrow[r] = topk_w[2 * t + j];
    }
}

// ---------------- GEMM1 (bf16 inputs): h = silu(x@W1^T) * (x@W3^T) ----------------
// 128x64 block tile, BK=32, 4 waves each computing 64x32 of BOTH G and U.
// Register budget: acc = 4*2*2 = 64 AGPRs (was 128 -> total >256 -> 1 wave/SIMD
// occupancy cliff, rounds 2/4 measured 11.3%). Double-buffered LDS,
// global_load_lds staging, one barrier per K-step.

__global__ __launch_bounds__(256) void gemm1_bf16_kernel(
    const bf16* __restrict__ xb, const bf16* __restrict__ wptr,
    long long wstride, int e_base,
    const int* __restrict__ offs, const int* __restrict__ rowtok,
    bf16* __restrict__ h) {
    const int ei = blockIdx.y >> 6;
    const int e = e_base + ei;
    const int tm = blockIdx.y & 63;
    const int mBeg = offs[e], mEnd = offs[e + 1];
    const int m0 = mBeg + tm * 128;
    if (m0 >= mEnd) return;
    const int n0 = blockIdx.x * 64;

    __shared__ alignas(16) bf16 As[2][128 * 32];
    __shared__ alignas(16) bf16 Bg[2][64 * 32];
    __shared__ alignas(16) bf16 Bu[2][64 * 32];

    const int tid = threadIdx.x;
    const int lane = tid & 63;
    const int wv = tid >> 6;
    const int wr = wv >> 1, wc = wv & 1;

    // A chunks: c in [0,512): row=c>>2, ks=(c&3)*8 ; two gl_lds calls.
    // B chunks: c=tid in [0,256): row=c>>2 in [0,64) ; one gl_lds call each.
    const int c0 = tid, c1 = tid + 256;
    const int ar0 = c0 >> 2, ks0 = (c0 & 3) * 8;
    const int ar1 = c1 >> 2, ks1 = (c1 & 3) * 8;
    const bf16* aG0 = xb + (size_t)rowtok[min(m0 + ar0, R_TOT - 1)] * H_DIM + ks0;
    const bf16* aG1 = xb + (size_t)rowtok[min(m0 + ar1, R_TOT - 1)] * H_DIM + ks1;
    const bf16* w13e = wptr + (size_t)ei * wstride;
    const bf16* bG0 = w13e + (size_t)(n0 + ar0) * H_DIM + ks0;
    const bf16* uG0 = w13e + (size_t)(I_DIM + n0 + ar0) * H_DIM + ks0;

    // wave-uniform LDS chunk element offsets (HW writes base + lane*16B)
    const int wb8 = (wv * 64) * 8;
    const int wb8b = (wv * 64 + 256) * 8;

#define STG1(B, KT)                          \
    gl_lds16(aG0 + (KT), &As[B][wb8]);       \
    gl_lds16(aG1 + (KT), &As[B][wb8b]);      \
    gl_lds16(bG0 + (KT), &Bg[B][wb8]);       \
    gl_lds16(uG0 + (KT), &Bu[B][wb8]);

    floatx4 accG[4][2] = {};
    floatx4 accU[4][2] = {};

    const int lr = lane & 15;
    const int kg = lane >> 4;

    // prologue: stage first tile, drain, barrier
    STG1(0, 0);
    __syncthreads();

    int cur = 0;
    for (int kt = 0; kt < H_DIM; kt += 32) {
        // issue next-tile async loads into the other buffer (in flight across compute)
        if (kt + 32 < H_DIM) { STG1(cur ^ 1, kt + 32); }

        short8 af[4], bgf[2], buf2[2];
#pragma unroll
        for (int i = 0; i < 4; i++)
            af[i] = *(const short8*)(&As[cur][(wr * 64 + i * 16 + lr) * 32 + kg * 8]);
#pragma unroll
        for (int j = 0; j < 2; j++) {
            bgf[j] = *(const short8*)(&Bg[cur][(wc * 32 + j * 16 + lr) * 32 + kg * 8]);
            buf2[j] = *(const short8*)(&Bu[cur][(wc * 32 + j * 16 + lr) * 32 + kg * 8]);
        }
#pragma unroll
        for (int i = 0; i < 4; i++)
#pragma unroll
            for (int j = 0; j < 2; j++) {
                accG[i][j] = __builtin_amdgcn_mfma_f32_16x16x32_bf16(af[i], bgf[j], accG[i][j], 0, 0, 0);
                accU[i][j] = __builtin_amdgcn_mfma_f32_16x16x32_bf16(af[i], buf2[j], accU[i][j], 0, 0, 0);
            }
        __syncthreads();  // waits prefetch (vmcnt0) + all lds reads, then barrier
        cur ^= 1;
    }
#undef STG1

    // epilogue: silu(g)*u -> h (C/D layout: col=lane&15, row=(lane>>4)*4+v)
    const int quad = lane >> 4;
#pragma unroll
    for (int i = 0; i < 4; i++) {
        const int grb = m0 + wr * 64 + i * 16 + quad * 4;
#pragma unroll
        for (int j = 0; j < 2; j++) {
            const int gc = n0 + wc * 32 + j * 16 + lr;
#pragma unroll
            for (int v = 0; v < 4; v++) {
                const int gr = grb + v;
                if (gr < mEnd) {
                    float g = accG[i][j][v];
                    float u = accU[i][j][v];
                    float s = g / (1.0f + __expf(-g));
                    h[(size_t)gr * I_DIM + gc] = __float2bfloat16(s * u);
                }
            }
        }
    }
}

// ---------------- GEMM2 (bf16 inputs): out[tok] += wrow * (h @ W2^T) ----------------
// 128x64 block tile, 4 waves each 64x32, acc = 32 AGPRs.

__global__ __launch_bounds__(256) void gemm2_bf16_kernel(
    const bf16* __restrict__ hbuf, const bf16* __restrict__ wptr,
    long long wstride, int e_base,
    const int* __restrict__ offs, const int* __restrict__ rowtok,
    const float* __restrict__ wrow, float* __restrict__ out) {
    const int ei = blockIdx.y >> 6;
    const int e = e_base + ei;
    const int tm = blockIdx.y & 63;
    const int mBeg = offs[e], mEnd = offs[e + 1];
    const int m0 = mBeg + tm * 128;
    if (m0 >= mEnd) return;
    const int n0 = blockIdx.x * 64;

    __shared__ alignas(16) bf16 As[2][128 * 32];
    __shared__ alignas(16) bf16 Bs[2][64 * 32];

    const int tid = threadIdx.x;
    const int lane = tid & 63;
    const int wv = tid >> 6;
    const int wr = wv >> 1, wc = wv & 1;

    const int c0 = tid, c1 = tid + 256;
    const int ar0 = c0 >> 2, ks0 = (c0 & 3) * 8;
    const int ar1 = c1 >> 2, ks1 = (c1 & 3) * 8;
    const bf16* aG0 = hbuf + (size_t)min(m0 + ar0, R_TOT - 1) * I_DIM + ks0;
    const bf16* aG1 = hbuf + (size_t)min(m0 + ar1, R_TOT - 1) * I_DIM + ks1;
    const bf16* w2e = wptr + (size_t)ei * wstride;
    const bf16* bG0 = w2e + (size_t)(n0 + ar0) * I_DIM + ks0;

    const int wb8 = (wv * 64) * 8;
    const int wb8b = (wv * 64 + 256) * 8;

#define STG2(B, KT)                          \
    gl_lds16(aG0 + (KT), &As[B][wb8]);       \
    gl_lds16(aG1 + (KT), &As[B][wb8b]);      \
    gl_lds16(bG0 + (KT), &Bs[B][wb8]);

    floatx4 acc[4][2] = {};
    const int lr = lane & 15;
    const int kg = lane >> 4;

    STG2(0, 0);
    __syncthreads();

    int cur = 0;
    for (int kt = 0; kt < I_DIM; kt += 32) {
        if (kt + 32 < I_DIM) { STG2(cur ^ 1, kt + 32); }

        short8 af[4], bf_[2];
#pragma unroll
        for (int i = 0; i < 4; i++)
            af[i] = *(const short8*)(&As[cur][(wr * 64 + i * 16 + lr) * 32 + kg * 8]);
#pragma unroll
        for (int j = 0; j < 2; j++)
            bf_[j] = *(const short8*)(&Bs[cur][(wc * 32 + j * 16 + lr) * 32 + kg * 8]);
#pragma unroll
        for (int i = 0; i < 4; i++)
#pragma unroll
            for (int j = 0; j < 2; j++)
                acc[i][j] = __builtin_amdgcn_mfma_f32_16x16x32_bf16(af[i], bf_[j], acc[i][j], 0, 0, 0);
        __syncthreads();
        cur ^= 1;
    }
#undef STG2

    const int quad = lane >> 4;
#pragma unroll
    for (int i = 0; i < 4; i++) {
        const int grb = m0 + wr * 64 + i * 16 + quad * 4;
#pragma unroll
        for (int j = 0; j < 2; j++) {
            const int gc = n0 + wc * 32 + j * 16 + lr;
#pragma unroll
            for (int v = 0; v < 4; v++) {
                const int gr = grb + v;
                if (gr < mEnd) {
                    const int t = rowtok[gr];
                    atomicAdd(&out[(size_t)t * H_DIM + gc], wrow[gr] * acc[i][j][v]);
                }
            }
        }
    }
}

// ---------------- fallback GEMMs (fp32 inputs, verified) ----------------

__global__ __launch_bounds__(256) void gemm1_f32_kernel(
    const float* __restrict__ x, const float* __restrict__ w13,
    const int* __restrict__ offs, const int* __restrict__ rowtok,
    bf16* __restrict__ h) {
    const int e = blockIdx.y >> 6;
    const int tm = blockIdx.y & 63;
    const int mBeg = offs[e], mEnd = offs[e + 1];
    const int m0 = mBeg + tm * 128;
    if (m0 >= mEnd) return;
    const int n0 = blockIdx.x * 128;

    __shared__ alignas(16) bf16 As[128 * 32];
    __shared__ alignas(16) bf16 Bg[128 * 32];
    __shared__ alignas(16) bf16 Bu[128 * 32];

    const int tid = threadIdx.x;
    const int lane = tid & 63;
    const int wv = tid >> 6;
    const int wr = wv >> 1, wc = wv & 1;

    const int c0 = tid, c1 = tid + 256;
    const int ar0 = c0 >> 2, ks0 = (c0 & 3) * 8;
    const int ar1 = c1 >> 2, ks1 = (c1 & 3) * 8;
    const int rr0 = min(m0 + ar0, R_TOT - 1);
    const int rr1 = min(m0 + ar1, R_TOT - 1);
    const float* aG0 = x + (size_t)rowtok[rr0] * H_DIM + ks0;
    const float* aG1 = x + (size_t)rowtok[rr1] * H_DIM + ks1;
    const float* w13e = w13 + (size_t)e * (2 * I_DIM) * H_DIM;
    const float* bG0 = w13e + (size_t)(n0 + ar0) * H_DIM + ks0;
    const float* bG1 = w13e + (size_t)(n0 + ar1) * H_DIM + ks1;
    const float* uG0 = w13e + (size_t)(I_DIM + n0 + ar0) * H_DIM + ks0;
    const float* uG1 = w13e + (size_t)(I_DIM + n0 + ar1) * H_DIM + ks1;

    floatx4 accG[4][4] = {};
    floatx4 accU[4][4] = {};

    const int lr = lane & 15;
    const int kg = lane >> 4;

    for (int kt = 0; kt < H_DIM; kt += 32) {
        short8 va0 = ld_cvt8(aG0 + kt);
        short8 va1 = ld_cvt8(aG1 + kt);
        short8 vg0 = ld_cvt8(bG0 + kt);
        short8 vg1 = ld_cvt8(bG1 + kt);
        short8 vu0 = ld_cvt8(uG0 + kt);
        short8 vu1 = ld_cvt8(uG1 + kt);
        __syncthreads();
        *(short8*)(As + c0 * 8) = va0;
        *(short8*)(As + c1 * 8) = va1;
        *(short8*)(Bg + c0 * 8) = vg0;
        *(short8*)(Bg + c1 * 8) = vg1;
        *(short8*)(Bu + c0 * 8) = vu0;
        *(short8*)(Bu + c1 * 8) = vu1;
        __syncthreads();

        short8 af[4], bgf[4], buf2[4];
#pragma unroll
        for (int i = 0; i < 4; i++)
            af[i] = *(const short8*)(As + (wr * 64 + i * 16 + lr) * 32 + kg * 8);
#pragma unroll
        for (int j = 0; j < 4; j++) {
            bgf[j] = *(const short8*)(Bg + (wc * 64 + j * 16 + lr) * 32 + kg * 8);
            buf2[j] = *(const short8*)(Bu + (wc * 64 + j * 16 + lr) * 32 + kg * 8);
        }
#pragma unroll
        for (int i = 0; i < 4; i++)
#pragma unroll
            for (int j = 0; j < 4; j++) {
                accG[i][j] = __builtin_amdgcn_mfma_f32_16x16x32_bf16(af[i], bgf[j], accG[i][j], 0, 0, 0);
                accU[i][j] = __builtin_amdgcn_mfma_f32_16x16x32_bf16(af[i], buf2[j], accU[i][j], 0, 0, 0);
            }
    }

    const int quad = lane >> 4;
#pragma unroll
    for (int i = 0; i < 4; i++) {
        const int grb = m0 + wr * 64 + i * 16 + quad * 4;
#pragma unroll
        for (int j = 0; j < 4; j++) {
            const int gc = n0 + wc * 64 + j * 16 + lr;
#pragma unroll
            for (int v = 0; v < 4; v++) {
                const int gr = grb + v;
                if (gr < mEnd) {
                    float g = accG[i][j][v];
                    float u = accU[i][j][v];
                    float s = g / (1.0f + __expf(-g));
                    h[(size_t)gr * I_DIM + gc] = __float2bfloat16(s * u);
                }
            }
        }
    }
}

__global__ __launch_bounds__(256) void gemm2_f32_kernel(
    const bf16* __restrict__ hbuf, const float* __restrict__ w2,
    const int* __restrict__ offs, const int* __restrict__ rowtok,
    const float* __restrict__ wrow, float* __restrict__ out) {
    const int e = blockIdx.y >> 6;
    const int tm = blockIdx.y & 63;
    const int mBeg = offs[e], mEnd = offs[e + 1];
    const int m0 = mBeg + tm * 128;
    if (m0 >= mEnd) return;
    const int n0 = blockIdx.x * 128;

    __shared__ alignas(16) bf16 As[128 * 32];
    __shared__ alignas(16) bf16 Bs[128 * 32];

    const int tid = threadIdx.x;
    const int lane = tid & 63;
    const int wv = tid >> 6;
    const int wr = wv >> 1, wc = wv & 1;

    const int c0 = tid, c1 = tid + 256;
    const int ar0 = c0 >> 2, ks0 = (c0 & 3) * 8;
    const int ar1 = c1 >> 2, ks1 = (c1 & 3) * 8;
    const bf16* aG0 = hbuf + (size_t)min(m0 + ar0, R_TOT - 1) * I_DIM + ks0;
    const bf16* aG1 = hbuf + (size_t)min(m0 + ar1, R_TOT - 1) * I_DIM + ks1;
    const float* w2e = w2 + (size_t)e * H_DIM * I_DIM;
    const float* bG0 = w2e + (size_t)(n0 + ar0) * I_DIM + ks0;
    const float* bG1 = w2e + (size_t)(n0 + ar1) * I_DIM + ks1;

    floatx4 acc[4][4] = {};
    const int lr = lane & 15;
    const int kg = lane >> 4;

    for (int kt = 0; kt < I_DIM; kt += 32) {
        short8 va0 = *(const short8*)(aG0 + kt);
        short8 va1 = *(const short8*)(aG1 + kt);
        short8 vb0 = ld_cvt8(bG0 + kt);
        short8 vb1 = ld_cvt8(bG1 + kt);
        __syncthreads();
        *(short8*)(As + c0 * 8) = va0;
        *(short8*)(As + c1 * 8) = va1;
        *(short8*)(Bs + c0 * 8) = vb0;
        *(short8*)(Bs + c1 * 8) = vb1;
        __syncthreads();

        short8 af[4], bf_[4];
#pragma unroll
        for (int i = 0; i < 4; i++)
            af[i] = *(const short8*)(As + (wr * 64 + i * 16 + lr) * 32 + kg * 8);
#pragma unroll
        for (int j = 0; j < 4; j++)
            bf_[j] = *(const short8*)(Bs + (wc * 64 + j * 16 + lr) * 32 + kg * 8);
#pragma unroll
        for (int i = 0; i < 4; i++)
#pragma unroll
            for (int j = 0; j < 4; j++)
                acc[i][j] = __builtin_amdgcn_mfma_f32_16x16x32_bf16(af[i], bf_[j], acc[i][j], 0, 0, 0);
    }

    const int quad = lane >> 4;
#pragma unroll
    for (int i = 0; i < 4; i++) {
        const int grb = m0 + wr * 64 + i * 16 + quad * 4;
#pragma unroll
        for (int j = 0; j < 4; j++) {
            const int gc = n0 + wc * 64 + j * 16 + lr;
#pragma unroll
            for (int v = 0; v < 4; v++) {
                const int gr = grb + v;
                if (gr < mEnd) {
                    const int t = rowtok[gr];
                    atomicAdd(&out[(size_t)t * H_DIM + gc], wrow[gr] * acc[i][j][v]);
                }
            }
        }
    }
}

// ---------------- launch ----------------

extern "C" void kernel_launch(void* const* d_in, const int* in_sizes, int n_in,
                              void* d_out, int out_size, void* d_ws, size_t ws_size,
                              hipStream_t stream) {
    const float* x = (const float*)d_in[0];
    const float* rl = (const float*)d_in[1];
    const float* w13 = (const float*)d_in[2];
    const float* w2 = (const float*)d_in[3];
    float* out = (float*)d_out;

    char* ws = (char*)d_ws;
    int* counts = (int*)(ws);                       // 8 ints
    int* offs = (int*)(ws + 256);                   // 9 ints
    int* cursor = (int*)(ws + 512);                 // 8 ints
    int* topk_id = (int*)(ws + 1024);               // 2*T ints   = 65536 B
    float* topk_w = (float*)(ws + 1024 + 65536);    // 2*T floats = 65536 B
    int* rowtok = (int*)(ws + 1024 + 2 * 65536);    // R ints     = 65536 B
    float* wrow = (float*)(ws + 1024 + 3 * 65536);  // R floats   = 65536 B

    const size_t BASE = 1024 + 4 * 65536;                       // 263,168
    const size_t H_BYTES = (size_t)R_TOT * I_DIM * 2;           // 92,274,688
    const size_t XB_BYTES = (size_t)T_TOK * H_DIM * 2;          // 16,777,216
    const size_t W13_BYTES = (size_t)E_NUM * 2 * I_DIM * H_DIM * 2;  // 92,274,688
    const size_t W13_SLICE = (size_t)2 * I_DIM * H_DIM * 2;     // 11,534,336
    const size_t W2_SLICE = (size_t)H_DIM * I_DIM * 2;          // 5,767,168

    bf16* h = (bf16*)(ws + BASE);
    bf16* xb = (bf16*)(ws + BASE + H_BYTES);
    bf16* wbuf = (bf16*)(ws + BASE + H_BYTES + XB_BYTES);  // w13b, later reused for w2b

    const size_t NEED_BULK = BASE + H_BYTES + XB_BYTES + W13_BYTES;   // ~202 MB
    const size_t NEED_SLICE = BASE + H_BYTES + XB_BYTES + W13_SLICE;  // ~121 MB

    // ---- routing (common) ----
    zero_out_kernel<<<(T_TOK * H_DIM) / (256 * 4), 256, 0, stream>>>(out);
    zero_counts_kernel<<<1, 64, 0, stream>>>(counts);
    router_kernel<<<(T_TOK + 255) / 256, 256, 0, stream>>>(rl, topk_id, topk_w, counts);
    offsets_kernel<<<1, 64, 0, stream>>>(counts, offs, cursor);
    scatter_kernel<<<(T_TOK + 255) / 256, 256, 0, stream>>>(topk_id, topk_w, cursor, rowtok, wrow);

    if (ws_size >= NEED_BULK) {
        // bulk pre-convert; w2b aliased into the w13b region after gemm1
        cvt_bf16_kernel<<<2048, 256, 0, stream>>>(x, xb, (T_TOK * H_DIM) / 8);
        cvt_bf16_kernel<<<2048, 256, 0, stream>>>(w13, wbuf, (int)(W13_BYTES / 2 / 8));
        gemm1_bf16_kernel<<<dim3(I_DIM / 64, E_NUM * 64), 256, 0, stream>>>(
            xb, wbuf, (long long)2 * I_DIM * H_DIM, 0, offs, rowtok, h);
        cvt_bf16_kernel<<<2048, 256, 0, stream>>>(w2, wbuf, (E_NUM * H_DIM * I_DIM) / 8);
        gemm2_bf16_kernel<<<dim3(H_DIM / 64, E_NUM * 64), 256, 0, stream>>>(
            h, wbuf, (long long)H_DIM * I_DIM, 0, offs, rowtok, wrow, out);
    } else if (ws_size >= NEED_SLICE) {
        // per-expert slice conversion into a single small buffer (stream-serial WAR safe)
        cvt_bf16_kernel<<<2048, 256, 0, stream>>>(x, xb, (T_TOK * H_DIM) / 8);
        for (int e = 0; e < E_NUM; e++) {
            cvt_bf16_kernel<<<1024, 256, 0, stream>>>(
                w13 + (size_t)e * 2 * I_DIM * H_DIM, wbuf, (int)(W13_SLICE / 2 / 8));
            gemm1_bf16_kernel<<<dim3(I_DIM / 64, 64), 256, 0, stream>>>(
                xb, wbuf, 0LL, e, offs, rowtok, h);
        }
        for (int e = 0; e < E_NUM; e++) {
            cvt_bf16_kernel<<<1024, 256, 0, stream>>>(
                w2 + (size_t)e * H_DIM * I_DIM, wbuf, (int)(W2_SLICE / 2 / 8));
            gemm2_bf16_kernel<<<dim3(H_DIM / 64, 64), 256, 0, stream>>>(
                h, wbuf, 0LL, e, offs, rowtok, wrow, out);
        }
    } else {
        // verified fallback: fp32-staging GEMMs (uses only BASE + h)
        gemm1_f32_kernel<<<dim3(I_DIM / 128, E_NUM * 64), 256, 0, stream>>>(
            x, w13, offs, rowtok, h);
        gemm2_f32_kernel<<<dim3(H_DIM / 128, E_NUM * 64), 256, 0, stream>>>(
            h, w2, offs, rowtok, wrow, out);
    }
}